// Round 16
// baseline (652.095 us; speedup 1.0000x reference)
//
#include <hip/hip_runtime.h>
#include <hip/hip_bf16.h>
#include <cstdint>
#include <cstddef>

typedef __attribute__((ext_vector_type(8))) short s16x8;
typedef __attribute__((ext_vector_type(4))) float f32x4;
typedef __attribute__((ext_vector_type(8))) _Float16 h8;
typedef __attribute__((ext_vector_type(4))) _Float16 h4;

#define TT 2048
#define BB 4
#define EE 1024
#define HH 16
#define DD 64
#define MR 8192   // T*B rows

#define MFMA_BF16(a,b,c) __builtin_amdgcn_mfma_f32_16x16x32_bf16(a,b,c,0,0,0)
#define MFMA_F16(a,b,c)  __builtin_amdgcn_mfma_f32_16x16x32_f16(a,b,c,0,0,0)

__device__ __forceinline__ ushort f2bf(float f) {
  uint32_t u = __float_as_uint(f);
  u += 0x7fffu + ((u >> 16) & 1u);   // RNE
  return (ushort)(u >> 16);
}

// global -> LDS async copy, 16B per lane. LDS dest must be wave-uniform base + lane*16.
#define GL2L(g, l) __builtin_amdgcn_global_load_lds( \
    (__attribute__((address_space(1))) void*)(g), \
    (__attribute__((address_space(3))) void*)(l), 16, 0, 0)

// ---------------------------------------------------------------- cast fp32->bf16
__global__ void cast_f32_bf16(const float* __restrict__ in, ushort* __restrict__ out, int n4) {
  int stride = gridDim.x * blockDim.x;
  for (int i = blockIdx.x * blockDim.x + threadIdx.x; i < n4; i += stride) {
    float4 v = ((const float4*)in)[i];
    ushort4 o;
    o.x = f2bf(v.x); o.y = f2bf(v.y); o.z = f2bf(v.z); o.w = f2bf(v.w);
    ((ushort4*)out)[i] = o;
  }
}

// ---------------------------------------------------------------- QKV projection
// Q scaled by 0.125*log2(e) (softmax computed with exp2) -> bf16 [b][h][t][d];
// K -> bf16 same; V -> f16 transposed [b][h][d][t].
__global__ __launch_bounds__(256) void gemm_qkv(
    const ushort* __restrict__ A, const ushort* __restrict__ W,
    const float* __restrict__ bias,
    ushort* __restrict__ Qb, ushort* __restrict__ Kb, ushort* __restrict__ Vt)
{
  __shared__ ushort As[128 * 32];
  __shared__ ushort Bs[128 * 32];
  const int K = EE;
  int tid = threadIdx.x;
  int bn = blockIdx.x, bm = blockIdx.y;
  int brow = bm * 128, bcol = bn * 128;
  int lane = tid & 63, wid = tid >> 6;
  int wm = wid >> 1, wn = wid & 1;
  int lr = lane & 15, kg = lane >> 4;

  f32x4 zero = {0.f, 0.f, 0.f, 0.f};
  f32x4 acc[4][4];
#pragma unroll
  for (int i = 0; i < 4; i++)
#pragma unroll
    for (int j = 0; j < 4; j++) acc[i][j] = zero;

  int r0 = tid >> 2, c0 = (tid & 3) * 8;
  const ushort* Abase = A + (size_t)brow * K;
  const ushort* Wbase = W + (size_t)bcol * K;

  for (int k0 = 0; k0 < K; k0 += 32) {
    __syncthreads();
    GL2L(Abase + (size_t)r0 * K + k0 + c0,        &As[tid * 8]);
    GL2L(Abase + (size_t)(r0 + 64) * K + k0 + c0, &As[(tid + 256) * 8]);
    GL2L(Wbase + (size_t)r0 * K + k0 + c0,        &Bs[tid * 8]);
    GL2L(Wbase + (size_t)(r0 + 64) * K + k0 + c0, &Bs[(tid + 256) * 8]);
    __syncthreads();
    s16x8 af[4], bfr[4];
#pragma unroll
    for (int i = 0; i < 4; i++) af[i]  = *(const s16x8*)&As[(wm * 64 + i * 16 + lr) * 32 + kg * 8];
#pragma unroll
    for (int j = 0; j < 4; j++) bfr[j] = *(const s16x8*)&Bs[(wn * 64 + j * 16 + lr) * 32 + kg * 8];
#pragma unroll
    for (int i = 0; i < 4; i++)
#pragma unroll
      for (int j = 0; j < 4; j++)
        acc[i][j] = MFMA_BF16(af[i], bfr[j], acc[i][j]);
  }

#pragma unroll
  for (int i = 0; i < 4; i++)
#pragma unroll
    for (int j = 0; j < 4; j++) {
      int n = bcol + wn * 64 + j * 16 + lr;
      float bv = bias[n];
      int sec = n >> 10;
      int hd = n & 1023;
      int h = hd >> 6, d = hd & 63;
#pragma unroll
      for (int e = 0; e < 4; e++) {
        int m = brow + wm * 64 + i * 16 + kg * 4 + e;
        int t = m >> 2, b = m & 3;
        float v = acc[i][j][e] + bv;
        size_t hoff = (size_t)(b * HH + h);
        if (sec == 0)      Qb[(hoff * TT + t) * DD + d] = f2bf(v * 0.180336880f); // 0.125*log2e
        else if (sec == 1) Kb[(hoff * TT + t) * DD + d] = f2bf(v);
        else { _Float16 hv = (_Float16)v; Vt[(hoff * DD + d) * TT + t] = *(ushort*)&hv; }
      }
    }
}

// ---------------------------------------------------------------- fused attention
// Head-level double-buffered pipeline. Block = (qt, b): 16 q-rows x 2048 keys
// x 16 heads, 512 thr, 1 block/CU (LDS ~133 KB), 2 waves/SIMD, fat registers.
// sc is 2 x 64 KB: while SM(h) runs on buffer b0, the NEXT head's K-loads are
// already in flight and its QK^T MFMAs write buffer b1 (T14 issue-early).
// Body per head: {loads(h+1,c0); SMrow0(h); mfma(h+1,c0); loads(h+1,c1);
// SMrow1(h); mfma(h+1,c1)} -> bar -> PV(h) partial+scr -> bar -> reduce -> bar.
__global__ __launch_bounds__(512) void attn_fused(
    const ushort* __restrict__ Qb, const ushort* __restrict__ Kb,
    const _Float16* __restrict__ Vt, ushort* __restrict__ attn,
    float* __restrict__ avgp)
{
  __shared__ __align__(16) _Float16 sc[2 * 16 * 2048];  // 128 KB double buffer
  __shared__ float scr[1024];          // 4 KB PV partial-reduction scratch
  __shared__ float pmax[2][16][8];     // per-row per-wave partial maxima (dbuf)
  __shared__ float invl[16];

  const int qt = blockIdx.x;      // 0..127
  const int b  = blockIdx.y;      // 0..3
  const int tid = threadIdx.x;
  const int lane = tid & 63;
  const int w = tid >> 6;         // wave 0..7
  const int m = lane & 15;
  const int kq = lane >> 4;       // frag k-chunk == C-layout row group
  const int t0 = qt * 16;
  const int xr_m = (m & 7) << 3;

  // per-thread avg accumulators, PACKED f16: row w*2 (av0) and w*2+1 (av1)
  h8 av0[4], av1[4];
#pragma unroll
  for (int c = 0; c < 4; c++)
#pragma unroll
    for (int j = 0; j < 8; j++) { av0[c][j] = (_Float16)0.f; av1[c][j] = (_Float16)0.f; }

  // SM row body: reads/writes buffer s0, pmax[bsel]; folds into AV.
#define SMROW(RR, AV) do {                                                     \
    const int r_ = (RR);                                                       \
    _Float16* rp_ = s0 + (size_t)r_ * 2048;                                    \
    const int xr_ = (r_ & 7) << 3;                                             \
    float mx_ = -3e38f;                                                        \
    _Pragma("unroll")                                                          \
    for (int j_ = 0; j_ < 8; ++j_) mx_ = fmaxf(mx_, pmax[bsel][r_][j_]);       \
    f32x4 lv0_ = {0.f,0.f,0.f,0.f}, lv1_ = {0.f,0.f,0.f,0.f};                  \
    _Pragma("unroll")                                                          \
    for (int c_ = 0; c_ < 4; ++c_) {                                           \
      h8 t_ = *(const h8*)&rp_[((c_ * 64 + lane) * 8) ^ xr_];                  \
      h8 e_;                                                                   \
      _Pragma("unroll")                                                        \
      for (int j_ = 0; j_ < 4; j_++) { float ef_ = exp2f((float)t_[j_] - mx_); lv0_[j_] += ef_; e_[j_] = (_Float16)ef_; } \
      _Pragma("unroll")                                                        \
      for (int j_ = 4; j_ < 8; j_++) { float ef_ = exp2f((float)t_[j_] - mx_); lv1_[j_-4] += ef_; e_[j_] = (_Float16)ef_; } \
      *(h8*)&rp_[((c_ * 64 + lane) * 8) ^ xr_] = e_;                           \
    }                                                                          \
    float l_ = ((lv0_[0]+lv0_[1])+(lv0_[2]+lv0_[3]))                           \
             + ((lv1_[0]+lv1_[1])+(lv1_[2]+lv1_[3]));                          \
    _Pragma("unroll")                                                          \
    for (int o_ = 32; o_; o_ >>= 1) l_ += __shfl_xor(l_, o_);                  \
    float inv_ = 1.0f / l_;                                                    \
    if (lane == 0) invl[r_] = inv_;                                            \
    _Float16 hinv_ = (_Float16)inv_;                                           \
    _Pragma("unroll")                                                          \
    for (int c_ = 0; c_ < 4; ++c_) {                                           \
      h8 e_ = *(const h8*)&rp_[((c_ * 64 + lane) * 8) ^ xr_];                  \
      _Pragma("unroll")                                                        \
      for (int j_ = 0; j_ < 8; j_++) AV[c_][j_] += e_[j_] * hinv_;             \
    }                                                                          \
  } while (0)

  // ---- prologue: QK^T for head 0 into buffer 0
  {
    const size_t bh = (size_t)b * HH;
    const ushort* qp = Qb + (bh * TT + t0) * DD;
    s16x8 q0 = *(const s16x8*)&qp[(size_t)m * DD + kq * 8];
    s16x8 q1 = *(const s16x8*)&qp[(size_t)m * DD + 32 + kq * 8];
    const ushort* kbase = Kb + bh * TT * DD;
    float mx0 = -3e38f;
#pragma unroll 4
    for (int i = 0; i < 16; ++i) {
      int nt = w * 16 + i;
      const ushort* kr = kbase + (size_t)(nt * 16 + m) * DD + kq * 8;
      s16x8 a0 = *(const s16x8*)kr;
      s16x8 a1 = *(const s16x8*)(kr + 32);
      f32x4 c0 = {0.f, 0.f, 0.f, 0.f};
      c0 = MFMA_BF16(a0, q0, c0);
      c0 = MFMA_BF16(a1, q1, c0);
      int ksw = (nt * 16 + kq * 4) ^ xr_m;
      h4 p0;
#pragma unroll
      for (int e = 0; e < 4; e++) { mx0 = fmaxf(mx0, c0[e]); p0[e] = (_Float16)c0[e]; }
      *(h4*)&sc[(size_t)m * 2048 + ksw] = p0;
    }
    mx0 = fmaxf(mx0, __shfl_xor(mx0, 16));
    mx0 = fmaxf(mx0, __shfl_xor(mx0, 32));
    if (lane < 16) pmax[0][m][w] = mx0;
  }
  __syncthreads();

  for (int h = 0; h < HH; ++h) {
    const int bsel = h & 1;
    _Float16* s0 = sc + (size_t)bsel * (16 * 2048);
    _Float16* s1 = sc + (size_t)(bsel ^ 1) * (16 * 2048);
    const size_t bh = (size_t)b * HH + h;
    const bool more = (h + 1) < HH;

    // next head's Q fragments + K base
    s16x8 q0n = {}, q1n = {};
    const ushort* kbn = nullptr;
    if (more) {
      const ushort* qpn = Qb + ((bh + 1) * TT + t0) * DD;
      q0n = *(const s16x8*)&qpn[(size_t)m * DD + kq * 8];
      q1n = *(const s16x8*)&qpn[(size_t)m * DD + 32 + kq * 8];
      kbn = Kb + (bh + 1) * TT * DD;
    }
    float mxn = -3e38f;
    s16x8 ka[8], kb[8];

    // ---- chunk 0 loads (h+1) -- in flight under SM row 0
    if (more) {
#pragma unroll
      for (int i = 0; i < 8; ++i) {
        const ushort* kr = kbn + (size_t)((w * 16 + i) * 16 + m) * DD + kq * 8;
        ka[i] = *(const s16x8*)kr;
        kb[i] = *(const s16x8*)(kr + 32);
      }
    }
    SMROW(w * 2 + 0, av0);
    if (more) {
#pragma unroll
      for (int i = 0; i < 8; ++i) {
        int nt = w * 16 + i;
        f32x4 c0 = {0.f, 0.f, 0.f, 0.f};
        c0 = MFMA_BF16(ka[i], q0n, c0);
        c0 = MFMA_BF16(kb[i], q1n, c0);
        int ksw = (nt * 16 + kq * 4) ^ xr_m;
        h4 p0;
#pragma unroll
        for (int e = 0; e < 4; e++) { mxn = fmaxf(mxn, c0[e]); p0[e] = (_Float16)c0[e]; }
        *(h4*)&s1[(size_t)m * 2048 + ksw] = p0;
      }
      // ---- chunk 1 loads -- in flight under SM row 1
#pragma unroll
      for (int i = 0; i < 8; ++i) {
        const ushort* kr = kbn + (size_t)((w * 16 + 8 + i) * 16 + m) * DD + kq * 8;
        ka[i] = *(const s16x8*)kr;
        kb[i] = *(const s16x8*)(kr + 32);
      }
    }
    SMROW(w * 2 + 1, av1);
    if (more) {
#pragma unroll
      for (int i = 0; i < 8; ++i) {
        int nt = w * 16 + 8 + i;
        f32x4 c0 = {0.f, 0.f, 0.f, 0.f};
        c0 = MFMA_BF16(ka[i], q0n, c0);
        c0 = MFMA_BF16(kb[i], q1n, c0);
        int ksw = (nt * 16 + kq * 4) ^ xr_m;
        h4 p0;
#pragma unroll
        for (int e = 0; e < 4; e++) { mxn = fmaxf(mxn, c0[e]); p0[e] = (_Float16)c0[e]; }
        *(h4*)&s1[(size_t)m * 2048 + ksw] = p0;
      }
      mxn = fmaxf(mxn, __shfl_xor(mxn, 16));
      mxn = fmaxf(mxn, __shfl_xor(mxn, 32));
      if (lane < 16) pmax[bsel ^ 1][m][w] = mxn;
    }
    __syncthreads();   // exp(h) ready in s0; invl ready; s1 fully written

    // ---- PV(h) on s0: wave = (d-tile, k-half), rows m; 2 indep chains
    {
      int dtl = w & 3, kh = w >> 2;
      const _Float16* vb = Vt + bh * DD * TT + (size_t)(dtl * 16 + m) * TT + kh * 1024 + kq * 8;
      const _Float16* ap = s0 + (size_t)m * 2048;
      f32x4 accA = {0.f, 0.f, 0.f, 0.f};
      f32x4 accB = {0.f, 0.f, 0.f, 0.f};
#pragma unroll 2
      for (int s = 0; s < 32; s += 2) {
        int ksw0 = (kh * 1024 + s * 32 + kq * 8) ^ xr_m;
        int ksw1 = (kh * 1024 + (s + 1) * 32 + kq * 8) ^ xr_m;
        h8 bv0 = *(const h8*)(vb + s * 32);
        h8 bv1 = *(const h8*)(vb + (s + 1) * 32);
        h8 a0 = *(const h8*)&ap[ksw0];
        h8 a1 = *(const h8*)&ap[ksw1];
        accA = MFMA_F16(a0, bv0, accA);
        accB = MFMA_F16(a1, bv1, accB);
      }
      if (kh == 1) {
#pragma unroll
        for (int e = 0; e < 4; e++)
          scr[dtl * 256 + (kq * 4 + e) * 16 + m] = accA[e] + accB[e];
      }
      __syncthreads();
      if (kh == 0) {
#pragma unroll
        for (int e = 0; e < 4; e++) {
          int ql = kq * 4 + e;
          float v0 = (accA[e] + accB[e] + scr[dtl * 256 + ql * 16 + m]) * invl[ql];
          attn[((size_t)(t0 + ql) * BB + b) * EE + h * DD + dtl * 16 + m] = f2bf(v0);
        }
      }
    }
    __syncthreads();   // s0 reads done (next iter's QK^T(h+2) overwrites s0)
  }
#undef SMROW

  // ---- write avg once: rows t0 + w*2, t0 + w*2+1
#pragma unroll
  for (int u = 0; u < 2; ++u) {
    float* gp = avgp + ((size_t)b * TT + t0 + w * 2 + u) * TT;
#pragma unroll
    for (int c = 0; c < 4; ++c) {
      int cb = (c * 64 + lane) * 8;
      const h8& a = u ? av1[c] : av0[c];
      float4 o0 = {(float)a[0] * 0.0625f, (float)a[1] * 0.0625f,
                   (float)a[2] * 0.0625f, (float)a[3] * 0.0625f};
      float4 o1 = {(float)a[4] * 0.0625f, (float)a[5] * 0.0625f,
                   (float)a[6] * 0.0625f, (float)a[7] * 0.0625f};
      ((float4*)(gp + cb))[0] = o0;
      ((float4*)(gp + cb))[1] = o1;
    }
  }
}

// ---------------------------------------------------------------- output projection
__global__ __launch_bounds__(256) void gemm_out(
    const ushort* __restrict__ A, const ushort* __restrict__ W,
    const float* __restrict__ bias, float* __restrict__ out)
{
  __shared__ ushort As[128 * 32];
  __shared__ ushort Bs[128 * 32];
  const int K = EE;
  int tid = threadIdx.x;
  int bn = blockIdx.x, bm = blockIdx.y;
  int brow = bm * 128, bcol = bn * 128;
  int lane = tid & 63, wid = tid >> 6;
  int wm = wid >> 1, wn = wid & 1;
  int lr = lane & 15, kg = lane >> 4;

  f32x4 zero = {0.f, 0.f, 0.f, 0.f};
  f32x4 acc[4][4];
#pragma unroll
  for (int i = 0; i < 4; i++)
#pragma unroll
    for (int j = 0; j < 4; j++) acc[i][j] = zero;

  int r0 = tid >> 2, c0 = (tid & 3) * 8;
  const ushort* Abase = A + (size_t)brow * K;
  const ushort* Wbase = W + (size_t)bcol * K;

  for (int k0 = 0; k0 < K; k0 += 32) {
    __syncthreads();
    GL2L(Abase + (size_t)r0 * K + k0 + c0,        &As[tid * 8]);
    GL2L(Abase + (size_t)(r0 + 64) * K + k0 + c0, &As[(tid + 256) * 8]);
    GL2L(Wbase + (size_t)r0 * K + k0 + c0,        &Bs[tid * 8]);
    GL2L(Wbase + (size_t)(r0 + 64) * K + k0 + c0, &Bs[(tid + 256) * 8]);
    __syncthreads();
    s16x8 af[4], bfr[4];
#pragma unroll
    for (int i = 0; i < 4; i++) af[i]  = *(const s16x8*)&As[(wm * 64 + i * 16 + lr) * 32 + kg * 8];
#pragma unroll
    for (int j = 0; j < 4; j++) bfr[j] = *(const s16x8*)&Bs[(wn * 64 + j * 16 + lr) * 32 + kg * 8];
#pragma unroll
    for (int i = 0; i < 4; i++)
#pragma unroll
      for (int j = 0; j < 4; j++)
        acc[i][j] = MFMA_BF16(af[i], bfr[j], acc[i][j]);
  }

#pragma unroll
  for (int i = 0; i < 4; i++)
#pragma unroll
    for (int j = 0; j < 4; j++) {
      int n = bcol + wn * 64 + j * 16 + lr;
      float bv = bias[n];
#pragma unroll
      for (int e = 0; e < 4; e++) {
        int m = brow + wm * 64 + i * 16 + kg * 4 + e;
        out[(size_t)m * EE + n] = acc[i][j][e] + bv;
      }
    }
}

// ---------------------------------------------------------------- launch
extern "C" void kernel_launch(void* const* d_in, const int* in_sizes, int n_in,
                              void* d_out, int out_size, void* d_ws, size_t ws_size,
                              hipStream_t stream) {
  const float* x  = (const float*)d_in[0];
  const float* w1 = (const float*)d_in[1];
  const float* b1 = (const float*)d_in[2];
  const float* w2 = (const float*)d_in[3];
  const float* b2 = (const float*)d_in[4];
  float* out = (float*)d_out;
  float* avg = out + (size_t)MR * EE;

  char* p = (char*)d_ws;
  ushort* Xb   = (ushort*)p; p += (size_t)MR * EE * 2;
  ushort* W1b  = (ushort*)p; p += (size_t)3 * EE * EE * 2;
  ushort* W2b  = (ushort*)p; p += (size_t)EE * EE * 2;
  ushort* Qb   = (ushort*)p; p += (size_t)BB * HH * TT * DD * 2;
  ushort* Kb   = (ushort*)p; p += (size_t)BB * HH * TT * DD * 2;
  ushort* Vt   = (ushort*)p; p += (size_t)BB * HH * TT * DD * 2;
  ushort* attn = (ushort*)p; p += (size_t)MR * EE * 2;
  (void)ws_size;

  cast_f32_bf16<<<1024, 256, 0, stream>>>(x,  Xb,  MR * EE / 4);
  cast_f32_bf16<<<512,  256, 0, stream>>>(w1, W1b, 3 * EE * EE / 4);
  cast_f32_bf16<<<256,  256, 0, stream>>>(w2, W2b, EE * EE / 4);
  gemm_qkv<<<dim3(24, 64), 256, 0, stream>>>(Xb, W1b, b1, Qb, Kb, Vt);
  attn_fused<<<dim3(TT / 16, BB), 512, 0, stream>>>(Qb, Kb, (const _Float16*)Vt, attn, avg);
  gemm_out<<<dim3(8, 64), 256, 0, stream>>>(attn, W2b, b2, out);
}

// Round 17
// 465.891 us; speedup vs baseline: 1.3997x; 1.3997x over previous
//
#include <hip/hip_runtime.h>
#include <hip/hip_bf16.h>
#include <cstdint>
#include <cstddef>

typedef __attribute__((ext_vector_type(8))) short s16x8;
typedef __attribute__((ext_vector_type(4))) float f32x4;
typedef __attribute__((ext_vector_type(8))) _Float16 h8;
typedef __attribute__((ext_vector_type(4))) _Float16 h4;

#define TT 2048
#define BB 4
#define EE 1024
#define HH 16
#define DD 64
#define MR 8192   // T*B rows

#define MFMA_BF16(a,b,c) __builtin_amdgcn_mfma_f32_16x16x32_bf16(a,b,c,0,0,0)
#define MFMA_F16(a,b,c)  __builtin_amdgcn_mfma_f32_16x16x32_f16(a,b,c,0,0,0)

__device__ __forceinline__ ushort f2bf(float f) {
  uint32_t u = __float_as_uint(f);
  u += 0x7fffu + ((u >> 16) & 1u);   // RNE
  return (ushort)(u >> 16);
}

// global -> LDS async copy, 16B per lane. LDS dest must be wave-uniform base + lane*16.
#define GL2L(g, l) __builtin_amdgcn_global_load_lds( \
    (__attribute__((address_space(1))) void*)(g), \
    (__attribute__((address_space(3))) void*)(l), 16, 0, 0)

// ---------------------------------------------------------------- cast fp32->bf16
__global__ void cast_f32_bf16(const float* __restrict__ in, ushort* __restrict__ out, int n4) {
  int stride = gridDim.x * blockDim.x;
  for (int i = blockIdx.x * blockDim.x + threadIdx.x; i < n4; i += stride) {
    float4 v = ((const float4*)in)[i];
    ushort4 o;
    o.x = f2bf(v.x); o.y = f2bf(v.y); o.z = f2bf(v.z); o.w = f2bf(v.w);
    ((ushort4*)out)[i] = o;
  }
}

// ---------------------------------------------------------------- QKV projection
// C[m][n] = sum_k A[m][k]*W[n][k] + bias[n];  m=(t*4+b), n = sec*1024 + h*64 + d
// Q scaled by 0.125 -> bf16 [b][h][t][d]; K -> bf16 same; V -> f16 transposed [b][h][d][t].
__global__ __launch_bounds__(256) void gemm_qkv(
    const ushort* __restrict__ A, const ushort* __restrict__ W,
    const float* __restrict__ bias,
    ushort* __restrict__ Qb, ushort* __restrict__ Kb, ushort* __restrict__ Vt)
{
  __shared__ ushort As[128 * 32];
  __shared__ ushort Bs[128 * 32];
  const int K = EE;
  int tid = threadIdx.x;
  int bn = blockIdx.x, bm = blockIdx.y;
  int brow = bm * 128, bcol = bn * 128;
  int lane = tid & 63, wid = tid >> 6;
  int wm = wid >> 1, wn = wid & 1;
  int lr = lane & 15, kg = lane >> 4;

  f32x4 zero = {0.f, 0.f, 0.f, 0.f};
  f32x4 acc[4][4];
#pragma unroll
  for (int i = 0; i < 4; i++)
#pragma unroll
    for (int j = 0; j < 4; j++) acc[i][j] = zero;

  int r0 = tid >> 2, c0 = (tid & 3) * 8;
  const ushort* Abase = A + (size_t)brow * K;
  const ushort* Wbase = W + (size_t)bcol * K;

  for (int k0 = 0; k0 < K; k0 += 32) {
    __syncthreads();
    GL2L(Abase + (size_t)r0 * K + k0 + c0,        &As[tid * 8]);
    GL2L(Abase + (size_t)(r0 + 64) * K + k0 + c0, &As[(tid + 256) * 8]);
    GL2L(Wbase + (size_t)r0 * K + k0 + c0,        &Bs[tid * 8]);
    GL2L(Wbase + (size_t)(r0 + 64) * K + k0 + c0, &Bs[(tid + 256) * 8]);
    __syncthreads();
    s16x8 af[4], bfr[4];
#pragma unroll
    for (int i = 0; i < 4; i++) af[i]  = *(const s16x8*)&As[(wm * 64 + i * 16 + lr) * 32 + kg * 8];
#pragma unroll
    for (int j = 0; j < 4; j++) bfr[j] = *(const s16x8*)&Bs[(wn * 64 + j * 16 + lr) * 32 + kg * 8];
#pragma unroll
    for (int i = 0; i < 4; i++)
#pragma unroll
      for (int j = 0; j < 4; j++)
        acc[i][j] = MFMA_BF16(af[i], bfr[j], acc[i][j]);
  }

#pragma unroll
  for (int i = 0; i < 4; i++)
#pragma unroll
    for (int j = 0; j < 4; j++) {
      int n = bcol + wn * 64 + j * 16 + lr;
      float bv = bias[n];
      int sec = n >> 10;
      int hd = n & 1023;
      int h = hd >> 6, d = hd & 63;
#pragma unroll
      for (int e = 0; e < 4; e++) {
        int m = brow + wm * 64 + i * 16 + kg * 4 + e;
        int t = m >> 2, b = m & 3;
        float v = acc[i][j][e] + bv;
        size_t hoff = (size_t)(b * HH + h);
        if (sec == 0)      Qb[(hoff * TT + t) * DD + d] = f2bf(v * 0.125f);
        else if (sec == 1) Kb[(hoff * TT + t) * DD + d] = f2bf(v);
        else { _Float16 hv = (_Float16)v; Vt[(hoff * DD + d) * TT + t] = *(ushort*)&hv; }
      }
    }
}

// ---------------------------------------------------------------- fused attention
// block = (qt, b): 32 q-rows x all 2048 keys x all 16 heads. 512 thr, 1 block/CU
// (LDS 140 KB), 2 waves/SIMD, fat register budget (no launch-bound cap) so the
// compiler can pipeline K/V loads 4-deep. Per head:
//   QK^T (swapped mfma, packed LDS writes, XOR swizzle) with FOLDED max-tracking
//   (f32 max on MFMA outputs + 2 shfl + pmax[32][8] reduce) -> no max sweep;
//   single exp sweep computing l and keeping the row's exp fragments in regs ->
//   av accumulated in packed-f16 regs after the l-ladder (no reload sweep);
//   PV f16 MFMA, 4 independent chains, (d-tile, k-half) waves + LDS reduction.
__global__ __launch_bounds__(512) void attn_fused(
    const ushort* __restrict__ Qb, const ushort* __restrict__ Kb,
    const _Float16* __restrict__ Vt, ushort* __restrict__ attn,
    float* __restrict__ avgp)
{
  __shared__ _Float16 sc[32 * 2048];   // 128 KB, column-swizzled: col ^ ((row&7)<<3)
  __shared__ float scr[2048];          // 8 KB PV partial-reduction scratch
  __shared__ float pmax[32][8];        // per-row per-wave partial maxima
  __shared__ float invl[32];

  const int qt = blockIdx.x;      // 0..63
  const int b  = blockIdx.y;      // 0..3
  const int tid = threadIdx.x;
  const int lane = tid & 63;
  const int w = tid >> 6;         // wave 0..7
  const int m = lane & 15;
  const int kq = lane >> 4;       // frag k-chunk == C-layout row group
  const int t0 = qt * 32;

  // per-thread avg accumulator, PACKED f16: rows w*4+u, cols (c*64+lane)*8+j
  h8 av[4][4];
#pragma unroll
  for (int u = 0; u < 4; u++)
#pragma unroll
    for (int c = 0; c < 4; c++)
#pragma unroll
      for (int j = 0; j < 8; j++) av[u][c][j] = (_Float16)0.f;

  for (int h = 0; h < HH; ++h) {
    const size_t bh = (size_t)b * HH + h;

    // ---- Q fragments (bf16), rows m and 16+m; Q pre-scaled by 1/8
    const ushort* qp = Qb + (bh * TT + t0) * DD;
    s16x8 q00 = *(const s16x8*)&qp[(size_t)m * DD + kq * 8];
    s16x8 q01 = *(const s16x8*)&qp[(size_t)m * DD + 32 + kq * 8];
    s16x8 q10 = *(const s16x8*)&qp[(size_t)(16 + m) * DD + kq * 8];
    s16x8 q11 = *(const s16x8*)&qp[(size_t)(16 + m) * DD + 32 + kq * 8];

    // ---- QK^T with folded running max: wave w owns keys w*256..+255
    const ushort* kbase = Kb + bh * TT * DD;
    float mx0 = -3e38f, mx1 = -3e38f;
#pragma unroll 4
    for (int i = 0; i < 16; ++i) {
      int nt = w * 16 + i;
      const ushort* kr = kbase + (size_t)(nt * 16 + m) * DD + kq * 8;
      s16x8 a0 = *(const s16x8*)kr;
      s16x8 a1 = *(const s16x8*)(kr + 32);
      f32x4 c0 = {0.f, 0.f, 0.f, 0.f}, c1 = {0.f, 0.f, 0.f, 0.f};
      c0 = MFMA_BF16(a0, q00, c0); c0 = MFMA_BF16(a1, q01, c0);
      c1 = MFMA_BF16(a0, q10, c1); c1 = MFMA_BF16(a1, q11, c1);
      // lane holds S[k = nt*16 + kq*4 + e][q = m (+16)] -> packed h4 writes
      int ksw = (nt * 16 + kq * 4) ^ ((m & 7) << 3);
      h4 p0, p1;
#pragma unroll
      for (int e = 0; e < 4; e++) {
        mx0 = fmaxf(mx0, c0[e]); mx1 = fmaxf(mx1, c1[e]);
        p0[e] = (_Float16)c0[e]; p1[e] = (_Float16)c1[e];
      }
      *(h4*)&sc[(size_t)m * 2048 + ksw] = p0;
      *(h4*)&sc[(size_t)(16 + m) * 2048 + ksw] = p1;
    }
    // reduce over the 4 kq lane-groups (lanes with equal m): xor 16, 32
    mx0 = fmaxf(mx0, __shfl_xor(mx0, 16)); mx0 = fmaxf(mx0, __shfl_xor(mx0, 32));
    mx1 = fmaxf(mx1, __shfl_xor(mx1, 16)); mx1 = fmaxf(mx1, __shfl_xor(mx1, 32));
    if (lane < 16) { pmax[m][w] = mx0; pmax[16 + m][w] = mx1; }
    __syncthreads();

    // ---- softmax: wave w owns rows w*4..w*4+3; ONE sweep (exp + l + av-frags)
#pragma unroll
    for (int u = 0; u < 4; ++u) {
      int r = w * 4 + u;
      _Float16* rp = &sc[(size_t)r * 2048];
      int xr = (r & 7) << 3;
      float mx = -3e38f;
#pragma unroll
      for (int j = 0; j < 8; ++j) mx = fmaxf(mx, pmax[r][j]);
      float l = 0.f;
      h8 eh[4];
#pragma unroll
      for (int c = 0; c < 4; ++c) {
        h8 t = *(const h8*)&rp[((c * 64 + lane) * 8) ^ xr];
        h8 e;
#pragma unroll
        for (int j = 0; j < 8; j++) { float ef = __expf((float)t[j] - mx); l += ef; e[j] = (_Float16)ef; }
        *(h8*)&rp[((c * 64 + lane) * 8) ^ xr] = e;
        eh[c] = e;
      }
#pragma unroll
      for (int o = 32; o; o >>= 1) l += __shfl_xor(l, o);
      float inv = 1.0f / l;
      if (lane == 0) invl[r] = inv;
      _Float16 hinv = (_Float16)inv;
#pragma unroll
      for (int c = 0; c < 4; ++c)
#pragma unroll
        for (int j = 0; j < 8; j++)
          av[u][c][j] += eh[c][j] * hinv;     // packs to v_pk_fma_f16
    }
    __syncthreads();

    // ---- PV: wave = (d-tile, k-half); rows m and 16+m; 4 independent chains
    {
      int dtl = w & 3, kh = w >> 2;
      const _Float16* vb = Vt + bh * DD * TT + (size_t)(dtl * 16 + m) * TT + kh * 1024 + kq * 8;
      const _Float16* a0p = &sc[(size_t)m * 2048];
      const _Float16* a1p = &sc[(size_t)(16 + m) * 2048];
      int xr = (m & 7) << 3;
      f32x4 accA0 = {0.f, 0.f, 0.f, 0.f}, accB0 = {0.f, 0.f, 0.f, 0.f};
      f32x4 accA1 = {0.f, 0.f, 0.f, 0.f}, accB1 = {0.f, 0.f, 0.f, 0.f};
#pragma unroll 2
      for (int s = 0; s < 32; s += 2) {
        int ksw0 = (kh * 1024 + s * 32 + kq * 8) ^ xr;
        int ksw1 = (kh * 1024 + (s + 1) * 32 + kq * 8) ^ xr;
        h8 bv0 = *(const h8*)(vb + s * 32);
        h8 bv1 = *(const h8*)(vb + (s + 1) * 32);
        h8 a00 = *(const h8*)&a0p[ksw0];
        h8 a01 = *(const h8*)&a0p[ksw1];
        h8 a10 = *(const h8*)&a1p[ksw0];
        h8 a11 = *(const h8*)&a1p[ksw1];
        accA0 = MFMA_F16(a00, bv0, accA0);
        accB0 = MFMA_F16(a01, bv1, accB0);
        accA1 = MFMA_F16(a10, bv0, accA1);
        accB1 = MFMA_F16(a11, bv1, accB1);
      }
      if (kh == 1) {
#pragma unroll
        for (int e = 0; e < 4; e++) {
          scr[(dtl * 2 + 0) * 256 + (kq * 4 + e) * 16 + m] = accA0[e] + accB0[e];
          scr[(dtl * 2 + 1) * 256 + (kq * 4 + e) * 16 + m] = accA1[e] + accB1[e];
        }
      }
      __syncthreads();
      if (kh == 0) {
#pragma unroll
        for (int e = 0; e < 4; e++) {
          int ql = kq * 4 + e;
          float v0 = (accA0[e] + accB0[e] + scr[(dtl * 2 + 0) * 256 + ql * 16 + m]) * invl[ql];
          float v1 = (accA1[e] + accB1[e] + scr[(dtl * 2 + 1) * 256 + ql * 16 + m]) * invl[16 + ql];
          attn[((size_t)(t0 + ql) * BB + b) * EE + h * DD + dtl * 16 + m] = f2bf(v0);
          attn[((size_t)(t0 + 16 + ql) * BB + b) * EE + h * DD + dtl * 16 + m] = f2bf(v1);
        }
      }
    }
    __syncthreads();   // sc/scr reads done before next head overwrites
  }

  // ---- write avg once: row t0 + w*4+u, cols (c*64+lane)*8 .. +7
#pragma unroll
  for (int u = 0; u < 4; ++u) {
    float* gp = avgp + ((size_t)b * TT + t0 + w * 4 + u) * TT;
#pragma unroll
    for (int c = 0; c < 4; ++c) {
      int cb = (c * 64 + lane) * 8;
      float4 o0 = {(float)av[u][c][0] * 0.0625f, (float)av[u][c][1] * 0.0625f,
                   (float)av[u][c][2] * 0.0625f, (float)av[u][c][3] * 0.0625f};
      float4 o1 = {(float)av[u][c][4] * 0.0625f, (float)av[u][c][5] * 0.0625f,
                   (float)av[u][c][6] * 0.0625f, (float)av[u][c][7] * 0.0625f};
      ((float4*)(gp + cb))[0] = o0;
      ((float4*)(gp + cb))[1] = o1;
    }
  }
}

// ---------------------------------------------------------------- output projection
__global__ __launch_bounds__(256) void gemm_out(
    const ushort* __restrict__ A, const ushort* __restrict__ W,
    const float* __restrict__ bias, float* __restrict__ out)
{
  __shared__ ushort As[128 * 32];
  __shared__ ushort Bs[128 * 32];
  const int K = EE;
  int tid = threadIdx.x;
  int bn = blockIdx.x, bm = blockIdx.y;
  int brow = bm * 128, bcol = bn * 128;
  int lane = tid & 63, wid = tid >> 6;
  int wm = wid >> 1, wn = wid & 1;
  int lr = lane & 15, kg = lane >> 4;

  f32x4 zero = {0.f, 0.f, 0.f, 0.f};
  f32x4 acc[4][4];
#pragma unroll
  for (int i = 0; i < 4; i++)
#pragma unroll
    for (int j = 0; j < 4; j++) acc[i][j] = zero;

  int r0 = tid >> 2, c0 = (tid & 3) * 8;
  const ushort* Abase = A + (size_t)brow * K;
  const ushort* Wbase = W + (size_t)bcol * K;

  for (int k0 = 0; k0 < K; k0 += 32) {
    __syncthreads();
    GL2L(Abase + (size_t)r0 * K + k0 + c0,        &As[tid * 8]);
    GL2L(Abase + (size_t)(r0 + 64) * K + k0 + c0, &As[(tid + 256) * 8]);
    GL2L(Wbase + (size_t)r0 * K + k0 + c0,        &Bs[tid * 8]);
    GL2L(Wbase + (size_t)(r0 + 64) * K + k0 + c0, &Bs[(tid + 256) * 8]);
    __syncthreads();
    s16x8 af[4], bfr[4];
#pragma unroll
    for (int i = 0; i < 4; i++) af[i]  = *(const s16x8*)&As[(wm * 64 + i * 16 + lr) * 32 + kg * 8];
#pragma unroll
    for (int j = 0; j < 4; j++) bfr[j] = *(const s16x8*)&Bs[(wn * 64 + j * 16 + lr) * 32 + kg * 8];
#pragma unroll
    for (int i = 0; i < 4; i++)
#pragma unroll
      for (int j = 0; j < 4; j++)
        acc[i][j] = MFMA_BF16(af[i], bfr[j], acc[i][j]);
  }

#pragma unroll
  for (int i = 0; i < 4; i++)
#pragma unroll
    for (int j = 0; j < 4; j++) {
      int n = bcol + wn * 64 + j * 16 + lr;
      float bv = bias[n];
#pragma unroll
      for (int e = 0; e < 4; e++) {
        int m = brow + wm * 64 + i * 16 + kg * 4 + e;
        out[(size_t)m * EE + n] = acc[i][j][e] + bv;
      }
    }
}

// ---------------------------------------------------------------- launch
extern "C" void kernel_launch(void* const* d_in, const int* in_sizes, int n_in,
                              void* d_out, int out_size, void* d_ws, size_t ws_size,
                              hipStream_t stream) {
  const float* x  = (const float*)d_in[0];
  const float* w1 = (const float*)d_in[1];
  const float* b1 = (const float*)d_in[2];
  const float* w2 = (const float*)d_in[3];
  const float* b2 = (const float*)d_in[4];
  float* out = (float*)d_out;
  float* avg = out + (size_t)MR * EE;

  char* p = (char*)d_ws;
  ushort* Xb   = (ushort*)p; p += (size_t)MR * EE * 2;
  ushort* W1b  = (ushort*)p; p += (size_t)3 * EE * EE * 2;
  ushort* W2b  = (ushort*)p; p += (size_t)EE * EE * 2;
  ushort* Qb   = (ushort*)p; p += (size_t)BB * HH * TT * DD * 2;
  ushort* Kb   = (ushort*)p; p += (size_t)BB * HH * TT * DD * 2;
  ushort* Vt   = (ushort*)p; p += (size_t)BB * HH * TT * DD * 2;
  ushort* attn = (ushort*)p; p += (size_t)MR * EE * 2;
  (void)ws_size;

  cast_f32_bf16<<<1024, 256, 0, stream>>>(x,  Xb,  MR * EE / 4);
  cast_f32_bf16<<<512,  256, 0, stream>>>(w1, W1b, 3 * EE * EE / 4);
  cast_f32_bf16<<<256,  256, 0, stream>>>(w2, W2b, EE * EE / 4);
  gemm_qkv<<<dim3(24, 64), 256, 0, stream>>>(Xb, W1b, b1, Qb, Kb, Vt);
  attn_fused<<<dim3(TT / 32, BB), 512, 0, stream>>>(Qb, Kb, (const _Float16*)Vt, attn, avg);
  gemm_out<<<dim3(8, 64), 256, 0, stream>>>(attn, W2b, b2, out);
}